// Round 7
// baseline (106.354 us; speedup 1.0000x reference)
//
#include <hip/hip_runtime.h>
#include <cstdint>
#include <cstddef>

typedef unsigned short u16;
typedef unsigned int   u32;
typedef __attribute__((ext_vector_type(4))) float f32x4;
typedef __attribute__((ext_vector_type(16))) float f32x16;
typedef __attribute__((ext_vector_type(8))) short bf16x8;
typedef __attribute__((ext_vector_type(4))) unsigned short u16x4;
typedef __attribute__((ext_vector_type(2))) u32 u32x2;
typedef __attribute__((ext_vector_type(4))) u32 u32x4;

#define DEVI static __device__ __forceinline__
#define MFMA16(a,b,c) __builtin_amdgcn_mfma_f32_16x16x32_bf16((a),(b),(c),0,0,0)
#define MFMA32(a,b,c) __builtin_amdgcn_mfma_f32_32x32x16_bf16((a),(b),(c),0,0,0)
#define BAR()   __builtin_amdgcn_s_barrier()
#define CFENCE() asm volatile("" ::: "memory")

DEVI u16 f2b(float f) {
  u32 u = __builtin_bit_cast(u32, f);
  u32 r = u + 0x7fffu + ((u >> 16) & 1u);
  return (u16)(r >> 16);
}

DEVI u32 pkbf(float a, float b) {
  u32 r;
  asm("v_cvt_pk_bf16_f32 %0, %1, %2" : "=v"(r) : "v"(a), "v"(b));
  return r;
}

DEVI void load_lds16(const void* g, void* l) {
  __builtin_amdgcn_global_load_lds(
      (const __attribute__((address_space(1))) u32*)g,
      (__attribute__((address_space(3))) u32*)l, 16, 0, 0);
}

DEVI int perm_o(int o) { return 4 * (o & 63) + (o >> 6); }   // o' = h*64+i -> o = 4i+h

// ---------------------------------------------------------------- weights prep
__global__ __launch_bounds__(256) void k_prep_w(
    const float* __restrict__ wq, const float* __restrict__ wk,
    const float* __restrict__ wv, const float* __restrict__ wm,
    const float* __restrict__ bq, const float* __restrict__ bk, const float* __restrict__ bv,
    u16* __restrict__ WQ, u16* __restrict__ WK, u16* __restrict__ WV, u16* __restrict__ WM,
    float* __restrict__ BQ, float* __restrict__ BK, float* __restrict__ BV)
{
  int row = blockIdx.x, t = threadIdx.x, m = blockIdx.y;
  if (m == 0)      WQ[row * 256 + t] = f2b(wq[perm_o(row) * 256 + t]);
  else if (m == 1) WK[row * 256 + t] = f2b(wk[perm_o(row) * 256 + t]);
  else if (m == 2) WV[row * 256 + t] = f2b(wv[perm_o(row) * 256 + t]);
  else if (m == 3) WM[row * 256 + t] = f2b(wm[row * 256 + perm_o(t)]);
  else if (row == 0) {
    BQ[t] = bq[perm_o(t)];
    BK[t] = bk[perm_o(t)];
    BV[t] = bv[perm_o(t)];
  }
}

// ---------------------------------------------- transpose+convert: [b][c][n]f32 -> [b][n][c]bf16
__global__ __launch_bounds__(256) void k_transpose(
    const float* __restrict__ q, const float* __restrict__ k, const float* __restrict__ v,
    u16* __restrict__ xq, u16* __restrict__ xk, u16* __restrict__ xv)
{
  __shared__ u16 tile[64][68];
  const int N = 2048, D = 256;
  int n0 = blockIdx.x * 64, c0 = blockIdx.y * 64;
  int b = blockIdx.z & 7, which = blockIdx.z >> 3;
  const float* src = (which == 0 ? q : which == 1 ? k : v) + (size_t)b * D * N;
  u16* dst = (which == 0 ? xq : which == 1 ? xk : xv) + (size_t)b * N * D;
  int t = threadIdx.x;
  int cl = t >> 4, ng = t & 15;
#pragma unroll
  for (int cc = 0; cc < 4; ++cc) {
    int c = cl + 16 * cc;
    f32x4 val = *(const f32x4*)&src[(size_t)(c0 + c) * N + n0 + ng * 4];
#pragma unroll
    for (int j = 0; j < 4; ++j) tile[c][ng * 4 + j] = f2b(val[j]);
  }
  __syncthreads();
  int n = t & 63, cq = t >> 6;
  union { u16 s[16]; u32x4 v4[2]; } pk;
#pragma unroll
  for (int j = 0; j < 16; ++j) pk.s[j] = tile[cq * 16 + j][n];
  u32x4* o = (u32x4*)&dst[(size_t)(n0 + n) * D + c0 + cq * 16];
  o[0] = pk.v4[0];
  o[1] = pk.v4[1];
}

// ---------------------------------------------------------------- GEMM 64x64 tile, BK=64
// Double-buffered staging; counted vmcnt + RAW s_barrier (no implicit vmcnt(0) drain).
template<int EPI>
__global__ __launch_bounds__(256, 4) void k_gemm(
    const u16* __restrict__ A, long sA,
    const u16* __restrict__ Bm, long sB,
    const float* __restrict__ bias,
    void* __restrict__ out, long sOut)
{
  __shared__ u16 lA[2][64 * 64];
  __shared__ u16 lB[2][64 * 64];
  int t = threadIdx.x, b = blockIdx.z;
  const u16* Ab = A + (size_t)b * sA + (size_t)blockIdx.x * 64 * 256;
  const u16* Bb = Bm + (size_t)b * sB + (size_t)blockIdx.y * 64 * 256;
  int l = t & 63, w = t >> 6, g = l >> 4, col = l & 15;
  int wr = w >> 1, wc = w & 1;
  f32x4 acc[2][2] = {};
  u32 sOf[2], sDs[2];
#pragma unroll
  for (int j = 0; j < 2; ++j) {
    int ci = t + 256 * j;
    int r = ci >> 3, c = ci & 7;
    sOf[j] = (u32)(r * 512 + ((c ^ (r & 7)) << 4));
    sDs[j] = (u32)(ci * 16);
  }
  auto stage = [&](int buf, int k0) {
#pragma unroll
    for (int j = 0; j < 2; ++j) {
      load_lds16((const char*)Ab + k0 * 2 + sOf[j], (char*)lA[buf] + sDs[j]);
      load_lds16((const char*)Bb + k0 * 2 + sOf[j], (char*)lB[buf] + sDs[j]);
    }
  };
  stage(0, 0);
  for (int s = 0; s < 4; ++s) {
    int cur = s & 1;
    if (s < 3) {
      stage(cur ^ 1, (s + 1) * 64);
      asm volatile("s_waitcnt vmcnt(4)" ::: "memory");
    } else {
      asm volatile("s_waitcnt vmcnt(0)" ::: "memory");
    }
    BAR(); CFENCE();
#pragma unroll
    for (int kc = 0; kc < 2; ++kc) {
      bf16x8 af[2], bfr[2];
#pragma unroll
      for (int mt = 0; mt < 2; ++mt) {
        int row = wr * 32 + mt * 16 + col;
        af[mt] = *(const bf16x8*)((const char*)lA[cur] + row * 128 + (((kc * 4 + g) ^ (row & 7)) << 4));
      }
#pragma unroll
      for (int nt = 0; nt < 2; ++nt) {
        int row = wc * 32 + nt * 16 + col;
        bfr[nt] = *(const bf16x8*)((const char*)lB[cur] + row * 128 + (((kc * 4 + g) ^ (row & 7)) << 4));
      }
#pragma unroll
      for (int mt = 0; mt < 2; ++mt)
#pragma unroll
        for (int nt = 0; nt < 2; ++nt)
          acc[mt][nt] = MFMA16(af[mt], bfr[nt], acc[mt][nt]);
    }
    if (s < 3) { CFENCE(); BAR(); }
  }
  if (EPI == 0) {
    u16* o = (u16*)out + (size_t)b * sOut;
#pragma unroll
    for (int nt = 0; nt < 2; ++nt) {
      int op = blockIdx.y * 64 + wc * 32 + nt * 16 + col;
      int hh = op >> 6, ii = op & 63;
      float bv = bias[op];
#pragma unroll
      for (int mt = 0; mt < 2; ++mt) {
        int nbase = blockIdx.x * 64 + wr * 32 + mt * 16 + g * 4;
#pragma unroll
        for (int r = 0; r < 4; ++r)
          o[((size_t)(hh * 2048 + nbase + r)) * 64 + ii] = f2b(acc[mt][nt][r] + bv);
      }
    }
  } else if (EPI == 1) {
    u16* o = (u16*)out + (size_t)b * sOut;
#pragma unroll
    for (int mt = 0; mt < 2; ++mt)
#pragma unroll
      for (int r = 0; r < 4; ++r) {
        int row = blockIdx.x * 64 + wr * 32 + mt * 16 + g * 4 + r;
        float bv = bias[row];
#pragma unroll
        for (int nt = 0; nt < 2; ++nt) {
          int cn = blockIdx.y * 64 + wc * 32 + nt * 16 + col;
          o[(size_t)row * 2048 + cn] = f2b(acc[mt][nt][r] + bv);
        }
      }
  } else {
    float* o = (float*)out + (size_t)b * sOut;
#pragma unroll
    for (int mt = 0; mt < 2; ++mt)
#pragma unroll
      for (int r = 0; r < 4; ++r) {
        int row = blockIdx.x * 64 + wr * 32 + mt * 16 + g * 4 + r;
        float bv = bias[row];
#pragma unroll
        for (int nt = 0; nt < 2; ++nt) {
          int cn = blockIdx.y * 64 + wc * 32 + nt * 16 + col;
          o[(size_t)row * 2048 + cn] = acc[mt][nt][r] + bv;
        }
      }
  }
}

// ---------------------------------------------------------------- flash attention
// 4 waves x 32 q-rows = 128 q/block, full KV sweep, 32 tiles of 64.
// Depth-3 prefetch over 4 tile-buffers (64 KB), counted vmcnt(8), ONE raw
// barrier per tile. XCD-aware block swizzle. Conflict-free (r>>1) XOR key.
// In-register streaming softmax; Sum(p) via ones-MFMA (no serial add chain).
__global__ __launch_bounds__(256, 2) void k_attn(
    const u16* __restrict__ Qt, const u16* __restrict__ Kt,
    const u16* __restrict__ Vw, u16* __restrict__ Xws)
{
  __shared__ u16 stg[4][2][4096];    // [buf][K|V][64 rows * 64] = 64 KB
  const float SC2 = 0.18033688011112042f;  // 0.125 * log2(e)
  int t = threadIdx.x, l = t & 63;
  int w = t >> 6;
  int hi = l >> 5, col = l & 31;
  // XCD-aware decode: all 16 q-blocks of a (b,h) land on one XCD (lin%8).
  int lin = blockIdx.x;
  int xcd = lin & 7, j = lin >> 3;     // j in 0..63
  int bh = xcd * 4 + (j >> 4);         // 4 (b,h) per XCD
  int nb = j & 15;
  int b = bh >> 2, hh = bh & 3;
  const u16* Qb = Qt + ((size_t)(b * 4 + hh) * 2048) * 64;
  const u16* Kb = Kt + ((size_t)(b * 4 + hh) * 2048) * 64;
  const u16* Vb = Vw + ((size_t)(b * 256 + hh * 64)) * 2048;
  int nq = nb * 128 + w * 32 + col;

  bf16x8 qf[4];
#pragma unroll
  for (int ks = 0; ks < 4; ++ks)
    qf[ks] = *(const bf16x8*)&Qb[(size_t)nq * 64 + ks * 16 + hi * 8];

  // staging offsets; swizzle key = (row>>1)&7  (8 residues per 16 lanes)
  u32 kSrc[2], vSrc[2], sDst[2];
#pragma unroll
  for (int jj = 0; jj < 2; ++jj) {
    int ci = t + 256 * jj;
    int r = ci >> 3, c = ci & 7;
    u32 sw = (u32)((c ^ ((r >> 1) & 7)) << 4);
    kSrc[jj] = (u32)(r * 128) + sw;
    vSrc[jj] = (u32)(r * 4096) + sw;
    sDst[jj] = (u32)(ci * 16);
  }
  u32 offC[4];
#pragma unroll
  for (int ks = 0; ks < 4; ++ks)
    offC[ks] = (u32)(((2 * ks + hi) ^ ((col >> 1) & 7)) << 4);

  bf16x8 ones;
  { union { u32 u[4]; bf16x8 v; } o; o.u[0] = o.u[1] = o.u[2] = o.u[3] = 0x3F803F80u; ones = o.v; }

  f32x16 xac0 = {}, xac1 = {}, xsum = {};
  float m_run = 0.0f;

  auto stage = [&](int buf, int tile) {
    const char* kb = (const char*)Kb + (size_t)tile * 8192;
    const char* vb = (const char*)Vb + (size_t)tile * 128;
#pragma unroll
    for (int jj = 0; jj < 2; ++jj)
      load_lds16(kb + kSrc[jj], (char*)stg[buf][0] + sDst[jj]);
#pragma unroll
    for (int jj = 0; jj < 2; ++jj)
      load_lds16(vb + vSrc[jj], (char*)stg[buf][1] + sDst[jj]);
  };

  stage(0, 0);
  stage(1, 1);
  for (int it = 0; it < 32; ++it) {
    int cur = it & 3;
    if (it < 30) {
      stage((it + 2) & 3, it + 2);
      // ratchet rescale (rare) — overlaps in-flight loads
      if (__any(xsum[0] > 16777216.0f)) {
        const float ds = 5.9604644775390625e-8f;   // 2^-24
        xac0 *= ds; xac1 *= ds; xsum *= ds;
        m_run += 24.0f;
      }
      asm volatile("s_waitcnt vmcnt(8)" ::: "memory");   // tile-it loads retired
    } else if (it == 30) {
      asm volatile("s_waitcnt vmcnt(4)" ::: "memory");
    } else {
      asm volatile("s_waitcnt vmcnt(0)" ::: "memory");
    }
    BAR(); CFENCE();                                     // single barrier per tile
    const char* kK = (const char*)stg[cur][0] + col * 128;
    const char* kV = (const char*)stg[cur][1] + col * 128;

    // ---- QK^T: S^T[m][n]
    f32x16 sac0 = {}, sac1 = {};
    __builtin_amdgcn_s_setprio(1);
#pragma unroll
    for (int ks = 0; ks < 4; ++ks) {
      bf16x8 kf0 = *(const bf16x8*)(kK + offC[ks]);
      bf16x8 kf1 = *(const bf16x8*)(kK + 4096 + offC[ks]);
      sac0 = MFMA32(kf0, qf[ks], sac0);
      sac1 = MFMA32(kf1, qf[ks], sac1);
    }
    __builtin_amdgcn_s_setprio(0);

    // ---- softmax (in-register, streaming) + P fragments
    bf16x8 pf[4];
#pragma unroll
    for (int mt = 0; mt < 2; ++mt) {
      const f32x16& sc = mt ? sac1 : sac0;
      float p[16];
#pragma unroll
      for (int r = 0; r < 16; ++r)
        p[r] = __builtin_amdgcn_exp2f(__builtin_fmaf(sc[r], SC2, -m_run));
      u32 A0 = pkbf(p[0],  p[1]),  B0 = pkbf(p[2],  p[3]);
      u32 A1 = pkbf(p[4],  p[5]),  B1 = pkbf(p[6],  p[7]);
      u32 A2 = pkbf(p[8],  p[9]),  B2 = pkbf(p[10], p[11]);
      u32 A3 = pkbf(p[12], p[13]), B3 = pkbf(p[14], p[15]);
      asm("v_permlane32_swap_b32 %0, %1" : "+v"(A0), "+v"(A1));
      asm("v_permlane32_swap_b32 %0, %1" : "+v"(B0), "+v"(B1));
      asm("v_permlane32_swap_b32 %0, %1" : "+v"(A2), "+v"(A3));
      asm("v_permlane32_swap_b32 %0, %1" : "+v"(B2), "+v"(B3));
      union { u32 u[4]; bf16x8 v; } f0, f1;
      f0.u[0] = A0; f0.u[1] = B0; f0.u[2] = A1; f0.u[3] = B1;
      f1.u[0] = A2; f1.u[1] = B2; f1.u[2] = A3; f1.u[3] = B3;
      pf[mt * 2 + 0] = f0.v;
      pf[mt * 2 + 1] = f1.v;
    }

    // ---- PV: x^T[i][n] += V^T[i][m] * P[m][n]; xsum += Sum_m P[m][n] (ones-MFMA)
    __builtin_amdgcn_s_setprio(1);
#pragma unroll
    for (int S = 0; S < 4; ++S) {
      bf16x8 vf0 = *(const bf16x8*)(kV + offC[S]);
      bf16x8 vf1 = *(const bf16x8*)(kV + 4096 + offC[S]);
      xac0 = MFMA32(vf0, pf[S], xac0);
      xac1 = MFMA32(vf1, pf[S], xac1);
      xsum = MFMA32(ones, pf[S], xsum);
    }
    __builtin_amdgcn_s_setprio(0);
    // no end-of-iter barrier: 4 buffers + pre-compute barrier make stage(t+2) safe
  }

  float inv = 1.0f / xsum[0];                 // full sum over all kv (ones-MFMA)
  u16* Ob = Xws + (size_t)b * 2048 * 256 + (size_t)nq * 256 + hh * 64;
#pragma unroll
  for (int it2 = 0; it2 < 2; ++it2) {
    const f32x16& xa = it2 ? xac1 : xac0;
#pragma unroll
    for (int rq = 0; rq < 4; ++rq) {
      float v0 = xa[4 * rq + 0] * inv;
      float v1 = xa[4 * rq + 1] * inv;
      float v2 = xa[4 * rq + 2] * inv;
      float v3 = xa[4 * rq + 3] * inv;
      u32x2 w2; w2[0] = pkbf(v0, v1); w2[1] = pkbf(v2, v3);
      *(u32x2*)&Ob[it2 * 32 + 8 * rq + 4 * hi] = w2;
    }
  }
}

// ---------------------------------------------------------------- launch
extern "C" void kernel_launch(void* const* d_in, const int* in_sizes, int n_in,
                              void* d_out, int out_size, void* d_ws, size_t ws_size,
                              hipStream_t stream)
{
  const float* q_in = (const float*)d_in[0];
  const float* k_in = (const float*)d_in[1];
  const float* v_in = (const float*)d_in[2];
  const float* w_q  = (const float*)d_in[3];
  const float* b_q  = (const float*)d_in[4];
  const float* w_k  = (const float*)d_in[5];
  const float* b_k  = (const float*)d_in[6];
  const float* w_v  = (const float*)d_in[7];
  const float* b_v  = (const float*)d_in[8];
  const float* w_m  = (const float*)d_in[9];
  const float* b_m  = (const float*)d_in[10];

  char* ws = (char*)d_ws;
  u16* XT_Q = (u16*)(ws + 0);           // [8][2048][256] bf16; reused as attn out
  u16* XT_K = (u16*)(ws + 8388608);
  u16* XT_V = (u16*)(ws + 16777216);
  u16* QT   = (u16*)(ws + 25165824);    // [8][4][2048][64]
  u16* KT   = (u16*)(ws + 33554432);
  u16* VW   = (u16*)(ws + 41943040);    // [8][256][2048]
  u16* WQ   = (u16*)(ws + 50331648);
  u16* WK   = (u16*)(ws + 50462720);
  u16* WV   = (u16*)(ws + 50593792);
  u16* WM   = (u16*)(ws + 50724864);
  float* BQ = (float*)(ws + 50855936);
  float* BK = (float*)(ws + 50856960);
  float* BV = (float*)(ws + 50857984);

  k_prep_w<<<dim3(256, 5), 256, 0, stream>>>(w_q, w_k, w_v, w_m, b_q, b_k, b_v,
                                             WQ, WK, WV, WM, BQ, BK, BV);
  k_transpose<<<dim3(32, 4, 24), 256, 0, stream>>>(q_in, k_in, v_in, XT_Q, XT_K, XT_V);
  k_gemm<0><<<dim3(32, 4, 8), 256, 0, stream>>>(XT_Q, 2048L * 256, WQ, 0, BQ, QT, 4L * 2048 * 64);
  k_gemm<0><<<dim3(32, 4, 8), 256, 0, stream>>>(XT_K, 2048L * 256, WK, 0, BK, KT, 4L * 2048 * 64);
  k_gemm<1><<<dim3(4, 32, 8), 256, 0, stream>>>(WV, 0, XT_V, 2048L * 256, BV, VW, 256L * 2048);
  k_attn<<<dim3(512), 256, 0, stream>>>(QT, KT, VW, XT_Q);
  k_gemm<2><<<dim3(4, 32, 8), 256, 0, stream>>>(WM, 0, XT_Q, 2048L * 256, b_m, d_out, 256L * 2048);
}